// Round 1
// baseline (509.486 us; speedup 1.0000x reference)
//
#include <hip/hip_runtime.h>

// ExpLeak: out[b,t,n] = alpha*out[b,t-1,n] + in[b,t,n], alpha = exp(-1/tau).
// B=16, T=1024, N=4096, fp32.
//
// R2 strategy: the single-pass chunked kernel (440 us) reads/writes 128 B per
// 16 KB row per block -> DRAM page/channel thrash, 1.2 TB/s effective.
// Replace with a 1.5-pass, fully-contiguous section scan:
//   K1: per (b, 32-row section) compute zero-init scan end  (read 256 MB)
//   K2: exclusive scan of section ends per column (8 MB, in-place)
//   K3: re-read input seeded with carry, write out          (read+write 512 MB)
// Every global access is float4, wave-contiguous (1 KB/row/wave), blocks cover
// full 16 KB rows. ~790 MB at ~6 TB/s ~= 140 us predicted.

constexpr int T = 1024;
constexpr int N = 4096;
constexpr int B = 16;
constexpr int N4 = N / 4;     // 1024 float4 per row
constexpr int TS = 32;        // rows per section
constexpr int SEC = T / TS;   // 32 sections

__device__ __forceinline__ float4 fma4(float a, float4 s, float4 x) {
  float4 r;
  r.x = fmaf(a, s.x, x.x);
  r.y = fmaf(a, s.y, x.y);
  r.z = fmaf(a, s.z, x.z);
  r.w = fmaf(a, s.w, x.w);
  return r;
}

// K1: per-(b,section): E = scan end over TS rows with zero initial state.
__global__ __launch_bounds__(1024) void k_partial(
    const float4* __restrict__ in4, const float* __restrict__ tau_mem,
    float4* __restrict__ part4) {
  const int b = blockIdx.x / SEC;
  const int s = blockIdx.x % SEC;
  const int n4 = threadIdx.x;  // 0..1023 -> full 16 KB row per block
  const float alpha = expf(-1.0f / tau_mem[0]);
  const float4* p = in4 + (size_t)(b * T + s * TS) * N4 + n4;
  float4 S = make_float4(0.f, 0.f, 0.f, 0.f);
#pragma unroll 8
  for (int j = 0; j < TS; ++j) {
    S = fma4(alpha, S, p[(size_t)j * N4]);
  }
  part4[(size_t)(b * SEC + s) * N4 + n4] = S;
}

// K2: in-place exclusive scan along sections per column.
// carry_into_s = GS_{s-1},  GS_s = alpha^TS * GS_{s-1} + E_s.
__global__ __launch_bounds__(256) void k_scan(
    float4* __restrict__ part4, const float* __restrict__ tau_mem) {
  const int t = blockIdx.x * blockDim.x + threadIdx.x;
  if (t >= B * N4) return;
  const int b = t >> 10;         // N4 = 1024
  const int n4 = t & (N4 - 1);
  const float aTS = expf(-(float)TS / tau_mem[0]);  // alpha^TS
  float4* col = part4 + (size_t)b * SEC * N4 + n4;
  float4 C = make_float4(0.f, 0.f, 0.f, 0.f);
  for (int s = 0; s < SEC; ++s) {
    float4 e = col[(size_t)s * N4];
    col[(size_t)s * N4] = C;     // overwrite end with carry (same thread owns col)
    C = fma4(aTS, C, e);
  }
}

// K3: seed running state with the section carry, redo the scan, write out.
// Identical per-element recurrence to the reference, just seeded.
__global__ __launch_bounds__(1024) void k_apply(
    const float4* __restrict__ in4, const float* __restrict__ tau_mem,
    const float4* __restrict__ part4, float4* __restrict__ out4) {
  const int b = blockIdx.x / SEC;
  const int s = blockIdx.x % SEC;
  const int n4 = threadIdx.x;
  const float alpha = expf(-1.0f / tau_mem[0]);
  float4 S = part4[(size_t)(b * SEC + s) * N4 + n4];
  const size_t base = (size_t)(b * T + s * TS) * N4 + n4;
#pragma unroll 4
  for (int j = 0; j < TS; ++j) {
    S = fma4(alpha, S, in4[base + (size_t)j * N4]);
    out4[base + (size_t)j * N4] = S;
  }
}

// ---------------- fallback: previous best single-pass kernel ----------------
constexpr int CHUNKS = 32;
constexpr int CLEN = 32;
constexpr int NCOL = 32;

__global__ __launch_bounds__(1024, 4) void expleak_kernel(
    const float* __restrict__ in, const float* __restrict__ tau_mem,
    float* __restrict__ out) {
  __shared__ float s_end[CHUNKS * NCOL];
  __shared__ float s_carry[CHUNKS * NCOL];

  const int tid = threadIdx.x;
  const int c = tid >> 5;
  const int l = tid & 31;
  const int b = blockIdx.x >> 7;
  const int ng = blockIdx.x & 127;

  const float tau = tau_mem[0];
  const float alpha = expf(-1.0f / tau);
  const float aL = expf(-(float)CLEN / tau);

  const unsigned base = ((unsigned)(b * T) + (unsigned)(c * CLEN)) * (unsigned)N
                        + (unsigned)(ng * NCOL + l);

  float v[CLEN];
#pragma unroll
  for (int j = 0; j < CLEN; ++j) v[j] = in[base + (unsigned)j * N];

  float s = 0.0f;
#pragma unroll
  for (int j = 0; j < CLEN; ++j) {
    s = fmaf(alpha, s, v[j]);
    v[j] = s;
  }
  s_end[c * NCOL + l] = s;
  __syncthreads();

  if (tid < NCOL) {
    float S = 0.0f;
#pragma unroll
    for (int cc = 0; cc < CHUNKS; ++cc) {
      s_carry[cc * NCOL + tid] = S;
      S = fmaf(aL, S, s_end[cc * NCOL + tid]);
    }
  }
  __syncthreads();

  const float carry = s_carry[c * NCOL + l];
  float f = alpha;
#pragma unroll
  for (int j = 0; j < CLEN; ++j) {
    out[base + (unsigned)j * N] = fmaf(f, carry, v[j]);
    f *= alpha;
  }
}

extern "C" void kernel_launch(void* const* d_in, const int* in_sizes, int n_in,
                              void* d_out, int out_size, void* d_ws, size_t ws_size,
                              hipStream_t stream) {
  const float* in = (const float*)d_in[0];
  const float* tau = (const float*)d_in[1];
  float* out = (float*)d_out;

  const size_t need = (size_t)B * SEC * N * sizeof(float);  // 8 MB of partials
  if (d_ws != nullptr && ws_size >= need) {
    float4* part4 = (float4*)d_ws;
    k_partial<<<B * SEC, 1024, 0, stream>>>((const float4*)in, tau, part4);
    k_scan<<<(B * N4) / 256, 256, 0, stream>>>(part4, tau);
    k_apply<<<B * SEC, 1024, 0, stream>>>((const float4*)in, tau, part4,
                                          (float4*)out);
  } else {
    expleak_kernel<<<B * (N / NCOL), CHUNKS * NCOL, 0, stream>>>(in, tau, out);
  }
}

// Round 2
// 495.658 us; speedup vs baseline: 1.0279x; 1.0279x over previous
//
#include <hip/hip_runtime.h>

// ExpLeak: out[b,t,n] = alpha*out[b,t-1,n] + in[b,t,n], alpha = exp(-1/tau).
// B=16, T=1024, N=4096, fp32.
//
// R3 strategy: R2's contiguous 3-kernel section scan was right, but it used
// d_ws for the 8 MB of partials -> the harness re-poisons the ENTIRE 1 GiB
// workspace per iteration (165 us fillBuffer seen in rocprof top-5), which
// erased the win. Same algorithm, ZERO workspace: partials live inside the
// output buffer.
//   K1: per (b, 32-row section): zero-init scan end E -> stored at out-row
//       s*TS (first row of the section's own output region).
//   K2: per column chain: in-place exclusive scan, E_s slot := carry-into-s
//       (= G_{s-1}), with section multiplier alpha^TS.
//   K3: per (b, section): read carry from own region start (into registers),
//       redo the seeded scan from the input, overwrite the region with finals.
// All global accesses float4, wave-contiguous, full 16 KB rows per block.
// Traffic ~790 MB total; no ws, no atomics, 3 stream-ordered dispatches.

constexpr int T = 1024;
constexpr int N = 4096;
constexpr int B = 16;
constexpr int N4 = N / 4;     // 1024 float4 per row
constexpr int TS = 32;        // rows per section
constexpr int SEC = T / TS;   // 32 sections

__device__ __forceinline__ float4 fma4(float a, float4 s, float4 x) {
  float4 r;
  r.x = fmaf(a, s.x, x.x);
  r.y = fmaf(a, s.y, x.y);
  r.z = fmaf(a, s.z, x.z);
  r.w = fmaf(a, s.w, x.w);
  return r;
}

// K1: E = zero-init scan end over the section's TS rows -> out[b][s*TS][:].
__global__ __launch_bounds__(1024) void k_partial(
    const float4* __restrict__ in4, const float* __restrict__ tau_mem,
    float4* __restrict__ out4) {
  const int b = blockIdx.x / SEC;
  const int s = blockIdx.x % SEC;
  const int n4 = threadIdx.x;  // full 16 KB row per block
  const float alpha = expf(-1.0f / tau_mem[0]);
  const size_t base = (size_t)(b * T + s * TS) * N4 + n4;
  float4 S = make_float4(0.f, 0.f, 0.f, 0.f);
#pragma unroll 8
  for (int j = 0; j < TS; ++j) {
    S = fma4(alpha, S, in4[base + (size_t)j * N4]);
  }
  out4[base] = S;  // E slot = first row of this section's region
}

// K2: per (b, n4 column): walk the 32 section slots in order;
// slot s := carry into section s (exclusive scan), C = aTS*C + E_s.
__global__ __launch_bounds__(256) void k_scan(
    float4* __restrict__ out4, const float* __restrict__ tau_mem) {
  const int t = blockIdx.x * blockDim.x + threadIdx.x;
  if (t >= B * N4) return;
  const int b = t >> 10;         // N4 = 1024
  const int n4 = t & (N4 - 1);
  const float aTS = expf(-(float)TS / tau_mem[0]);  // alpha^TS
  float4* col = out4 + (size_t)b * T * N4 + n4;
  float4 C = make_float4(0.f, 0.f, 0.f, 0.f);
  for (int s = 0; s < SEC; ++s) {
    const size_t off = (size_t)(s * TS) * N4;
    float4 e = col[off];
    col[off] = C;                // carry INTO section s (same thread owns col)
    C = fma4(aTS, C, e);
  }
}

// K3: seed with the carry stored at the region's first row, redo the scan
// from the input, overwrite the region with final values.
__global__ __launch_bounds__(1024) void k_apply(
    const float4* __restrict__ in4, const float* __restrict__ tau_mem,
    float4* __restrict__ out4) {
  const int b = blockIdx.x / SEC;
  const int s = blockIdx.x % SEC;
  const int n4 = threadIdx.x;
  const float alpha = expf(-1.0f / tau_mem[0]);
  const size_t base = (size_t)(b * T + s * TS) * N4 + n4;
  float4 S = out4[base];  // carry into this section (read BEFORE overwrite)
#pragma unroll 4
  for (int j = 0; j < TS; ++j) {
    S = fma4(alpha, S, in4[base + (size_t)j * N4]);
    out4[base + (size_t)j * N4] = S;
  }
}

extern "C" void kernel_launch(void* const* d_in, const int* in_sizes, int n_in,
                              void* d_out, int out_size, void* d_ws, size_t ws_size,
                              hipStream_t stream) {
  const float4* in4 = (const float4*)d_in[0];
  const float* tau = (const float*)d_in[1];
  float4* out4 = (float4*)d_out;

  k_partial<<<B * SEC, 1024, 0, stream>>>(in4, tau, out4);
  k_scan<<<(B * N4) / 256, 256, 0, stream>>>(out4, tau);
  k_apply<<<B * SEC, 1024, 0, stream>>>(in4, tau, out4);
}